// Round 6
// baseline (380.445 us; speedup 1.0000x reference)
//
#include <hip/hip_runtime.h>
#include <math.h>

#define D 64
#define MIN_NORM 1e-15f
#define PROJ_MAXNORM 0.996f   // (1 - 4e-3) / sqrt(c), c=1
#define SCAN_T 1024

__device__ __forceinline__ float wave_reduce_sum(float v) {
#pragma unroll
    for (int m = 1; m < 64; m <<= 1)
        v += __shfl_xor(v, m, 64);
    return v;
}

// artanh for z >= 0 (input is a norm), fast log + rcp
__device__ __forceinline__ float fast_artanh(float z) {
    z = fminf(z, 1.0f - 1e-7f);
    return 0.5f * __logf((1.0f + z) * __builtin_amdgcn_rcpf(1.0f - z));
}

__device__ __forceinline__ unsigned short f2bf(float x) {  // RNE
    unsigned int b = __float_as_uint(x);
    return (unsigned short)((b + 0x7fffu + ((b >> 16) & 1u)) >> 16);
}

__device__ __forceinline__ float bf2f(unsigned short u) {
    return __uint_as_float(((unsigned int)u) << 16);
}

// Kernel 1: per-node bf16 copy of x + packed (sqnorm, logmap0-scale) float2
__global__ void prep_kernel(const float* __restrict__ x,
                            unsigned short* __restrict__ x_bf,
                            float2* __restrict__ snf,
                            int N) {
    int node = blockIdx.x * 4 + (threadIdx.x >> 6);
    int lane = threadIdx.x & 63;
    if (node >= N) return;
    float v = x[node * D + lane];
    float s = wave_reduce_sum(v * v);
    float pn = fmaxf(sqrtf(s), MIN_NORM);
    float f = fast_artanh(pn) / pn;
    x_bf[node * D + lane] = f2bf(v);
    if (lane == 0) snf[node] = make_float2(s, f);
}

// Kernel 2: histogram of row indices
__global__ void count_kernel(const int* __restrict__ row_idx,
                             int* __restrict__ count, int E) {
    int e = blockIdx.x * 256 + threadIdx.x;
    if (e < E) atomicAdd(&count[row_idx[e]], 1);
}

// Kernel 3a: per-block exclusive scan, block totals to bsums
__global__ void scan1_kernel(const int* __restrict__ in,
                             int* __restrict__ out,
                             int* __restrict__ bsums, int N) {
    __shared__ int tmp[SCAN_T];
    int tid = threadIdx.x, gid = blockIdx.x * SCAN_T + tid;
    int v = (gid < N) ? in[gid] : 0;
    tmp[tid] = v;
    __syncthreads();
    for (int off = 1; off < SCAN_T; off <<= 1) {
        int t = (tid >= off) ? tmp[tid - off] : 0;
        __syncthreads();
        tmp[tid] += t;
        __syncthreads();
    }
    if (gid < N) out[gid] = tmp[tid] - v;          // exclusive
    if (tid == SCAN_T - 1) bsums[blockIdx.x] = tmp[tid];  // inclusive total
}

// Kernel 3b: single-block exclusive scan of block totals
__global__ void scan2_kernel(const int* __restrict__ bsums,
                             int* __restrict__ boffs, int B) {
    __shared__ int tmp[SCAN_T];
    int tid = threadIdx.x;
    int v = (tid < B) ? bsums[tid] : 0;
    tmp[tid] = v;
    __syncthreads();
    for (int off = 1; off < SCAN_T; off <<= 1) {
        int t = (tid >= off) ? tmp[tid - off] : 0;
        __syncthreads();
        tmp[tid] += t;
        __syncthreads();
    }
    if (tid < B) boffs[tid] = tmp[tid] - v;
}

// Kernel 3c: add block offsets -> row_start; init cursor; row_start[N]=E
__global__ void scan3_kernel(int* __restrict__ row_start,
                             int* __restrict__ cursor,
                             const int* __restrict__ boffs, int N, int E) {
    int gid = blockIdx.x * SCAN_T + threadIdx.x;
    if (gid < N) {
        int v = row_start[gid] + boffs[blockIdx.x];
        row_start[gid] = v;
        cursor[gid] = v;
    }
    if (gid == 0) row_start[N] = E;
}

// Kernel 4: place col indices into CSR order (1 int atomic + 4B store/edge)
__global__ void place_kernel(const int* __restrict__ row_idx,
                             const int* __restrict__ col_idx,
                             int* __restrict__ cursor,
                             int* __restrict__ col_sorted, int E) {
    int e = blockIdx.x * 256 + threadIdx.x;
    if (e >= E) return;
    int pos = atomicAdd(&cursor[row_idx[e]], 1);
    col_sorted[pos] = col_idx[e];
}

// Kernel 5: fused per-row kernel. Wave per row, lane per feature.
// Per 16-edge chunk: 16 coalesced neighbor-row loads -> per-lane partials,
// butterfly multi-reduce -> 16 dots (dot j lands on lanes with lane&15==j),
// weight math once per wave for 16 edges, 16 shfl-broadcast FMAs aggregate.
__global__ void fused_kernel(const float* __restrict__ x,
                             const unsigned short* __restrict__ x_bf,
                             const float2* __restrict__ snf,
                             const int* __restrict__ col_sorted,
                             const int* __restrict__ row_start,
                             const float* __restrict__ beta,
                             const float* __restrict__ con,
                             float* __restrict__ out, int N) {
    int row = blockIdx.x * 4 + (threadIdx.x >> 6);
    int lane = threadIdx.x & 63;
    if (row >= N) return;
    int start = row_start[row];
    int end = row_start[row + 1];
    float xr = x[row * D + lane];       // this lane's feature of row r (fp32)
    float x2 = snf[row].x;
    float B = beta[0], C0 = con[0];
    int jj = lane & 15;                 // this lane's edge slot within a chunk
    float acc = 0.0f, wacc = 0.0f;

    for (int j0 = start; j0 < end; j0 += 16) {
        int c_own = (j0 + jj < end) ? col_sorted[j0 + jj] : 0;
        float xv[16];
        float v[16];
#pragma unroll
        for (int j = 0; j < 16; j++) {
            int cj = __shfl(c_own, j, 16);           // wave-uniform col j
            float xc = bf2f(x_bf[cj * D + lane]);    // coalesced 128B row
            xv[j] = xc;
            v[j] = xc * xr;                          // partial dot
        }
        // butterfly multi-reduce: 16 dots in 17 shfls.
        // After step k (k=0..3), slot i holds orig index 2i + lane-bit-k path;
        // final: lane l holds sum over its 16-lane group for edge (l&15).
#pragma unroll
        for (int k = 0; k < 4; k++) {
            bool hi = (lane >> k) & 1;
            int half = 8 >> k;
#pragma unroll
            for (int i = 0; i < half; i++) {
                float a = v[2 * i], b = v[2 * i + 1];
                float keep = hi ? b : a;
                float send = hi ? a : b;
                v[i] = keep + __shfl_xor(send, 1 << k, 64);
            }
        }
        float d = v[0];
        d += __shfl_xor(d, 16, 64);
        d += __shfl_xor(d, 32, 64);     // full 64-lane dot for edge jj

        // weight math: each lane handles its own edge jj (4 redundant copies)
        float2 sf = snf[c_own];         // (y2, f_col)
        float y2 = sf.x;
        float a_ = 1.0f - 2.0f * d + y2;
        float b_ = 1.0f - x2;
        float num2 = a_ * a_ * x2 - 2.0f * a_ * b_ * d + b_ * b_ * y2;
        float den = fmaxf(1.0f - 2.0f * d + x2 * y2, MIN_NORM);
        float man = sqrtf(fmaxf(num2, 0.0f)) * __builtin_amdgcn_rcpf(den);
        float at = fast_artanh(man);
        float w = __expf(-B * 4.0f * at * at + C0);  // dist^2 = 4*artanh^2
        if (j0 + jj >= end) w = 0.0f;                 // mask tail slots
        float wf = w * sf.y;
        wacc += w;
#pragma unroll
        for (int j = 0; j < 16; j++) {
            float wfj = __shfl(wf, j, 16);
            acc += wfj * xv[j];
        }
    }
    // wsum: reduce wacc within the 16-lane group (each group has all 16 edges)
#pragma unroll
    for (int m = 1; m < 16; m <<= 1)
        wacc += __shfl_xor(wacc, m, 64);

    float s = acc / (wacc + 1e-10f);
    float n2 = wave_reduce_sum(s * s);
    float un = fmaxf(sqrtf(n2), MIN_NORM);
    float tt = tanhf(un) / un;                     // expmap0 scale
    float o = tt * s;
    float on = tt * sqrtf(n2);                     // ||o||
    if (on > PROJ_MAXNORM)
        o = o / fmaxf(on, MIN_NORM) * PROJ_MAXNORM;
    out[row * D + lane] = o;
}

extern "C" void kernel_launch(void* const* d_in, const int* in_sizes, int n_in,
                              void* d_out, int out_size, void* d_ws, size_t ws_size,
                              hipStream_t stream) {
    const float* x    = (const float*)d_in[0];
    const float* beta = (const float*)d_in[1];
    const float* con  = (const float*)d_in[2];
    const int*   ei   = (const int*)d_in[3];

    int N = in_sizes[0] / D;
    int E = in_sizes[3] / 2;
    const int* row_idx = ei;
    const int* col_idx = ei + E;
    float* out = (float*)d_out;

    // workspace layout (8B-aligned first)
    float2*         snf   = (float2*)d_ws;                 // N float2
    unsigned short* x_bf  = (unsigned short*)(snf + N);    // N*D bf16 (12.8 MB)
    int*    col_sorted = (int*)(x_bf + (size_t)N * D);     // E ints (6.4 MB)
    int*    count    = col_sorted + E;                     // N ints
    int*    row_start= count + N;                          // N+1 ints
    int*    cursor   = row_start + N + 1;                  // N ints
    int*    bsums    = cursor + N;                         // SCAN_T ints
    int*    boffs    = bsums + SCAN_T;                     // SCAN_T ints

    hipMemsetAsync(count, 0, (size_t)N * sizeof(int), stream);

    int nodeBlocks = (N + 3) / 4;
    prep_kernel<<<nodeBlocks, 256, 0, stream>>>(x, x_bf, snf, N);

    count_kernel<<<(E + 255) / 256, 256, 0, stream>>>(row_idx, count, E);

    int SB = (N + SCAN_T - 1) / SCAN_T;   // 98 blocks for N=100K
    scan1_kernel<<<SB, SCAN_T, 0, stream>>>(count, row_start, bsums, N);
    scan2_kernel<<<1, SCAN_T, 0, stream>>>(bsums, boffs, SB);
    scan3_kernel<<<SB, SCAN_T, 0, stream>>>(row_start, cursor, boffs, N, E);

    place_kernel<<<(E + 255) / 256, 256, 0, stream>>>(row_idx, col_idx,
                                                      cursor, col_sorted, E);

    fused_kernel<<<nodeBlocks, 256, 0, stream>>>(x, x_bf, snf, col_sorted,
                                                 row_start, beta, con, out, N);
}

// Round 7
// 289.232 us; speedup vs baseline: 1.3154x; 1.3154x over previous
//
#include <hip/hip_runtime.h>
#include <math.h>

#define D 64
#define MIN_NORM 1e-15f
#define PROJ_MAXNORM 0.996f   // (1 - 4e-3) / sqrt(c), c=1
#define SCAN_T 1024
#define CPAD 16               // one counter per 64B cache line

__device__ __forceinline__ float wave_reduce_sum(float v) {
#pragma unroll
    for (int m = 1; m < 64; m <<= 1)
        v += __shfl_xor(v, m, 64);
    return v;
}

// artanh for z >= 0 (input is a norm), fast log + rcp
__device__ __forceinline__ float fast_artanh(float z) {
    z = fminf(z, 1.0f - 1e-7f);
    return 0.5f * __logf((1.0f + z) * __builtin_amdgcn_rcpf(1.0f - z));
}

__device__ __forceinline__ unsigned short f2bf(float x) {  // RNE
    unsigned int b = __float_as_uint(x);
    return (unsigned short)((b + 0x7fffu + ((b >> 16) & 1u)) >> 16);
}

__device__ __forceinline__ float bf2f(unsigned short u) {
    return __uint_as_float(((unsigned int)u) << 16);
}

// Kernel 1: per-node bf16 copy of x + packed (sqnorm, logmap0-scale) float2
__global__ void prep_kernel(const float* __restrict__ x,
                            unsigned short* __restrict__ x_bf,
                            float2* __restrict__ snf,
                            int N) {
    int node = blockIdx.x * 4 + (threadIdx.x >> 6);
    int lane = threadIdx.x & 63;
    if (node >= N) return;
    float v = x[node * D + lane];
    float s = wave_reduce_sum(v * v);
    float pn = fmaxf(sqrtf(s), MIN_NORM);
    float f = fast_artanh(pn) / pn;
    x_bf[node * D + lane] = f2bf(v);
    if (lane == 0) snf[node] = make_float2(s, f);
}

// Kernel 2: count + rank in one pass. Padded counters (64B/counter) kill
// same-line serialization; 4 edges/thread give 4 independent atomic chains;
// seq stored COALESCED (the atomic return no longer feeds a scattered store).
__global__ void count_rank_kernel(const int* __restrict__ row_idx,
                                  int* __restrict__ count,
                                  int* __restrict__ seq, int E) {
    int t = blockIdx.x * 256 + threadIdx.x;
    int e0 = t * 4;
    if (e0 + 3 < E) {
        int4 r = *(const int4*)(row_idx + e0);
        int4 s;
        s.x = atomicAdd(&count[r.x * CPAD], 1);
        s.y = atomicAdd(&count[r.y * CPAD], 1);
        s.z = atomicAdd(&count[r.z * CPAD], 1);
        s.w = atomicAdd(&count[r.w * CPAD], 1);
        *(int4*)(seq + e0) = s;
    } else {
        for (int e = e0; e < E; e++)
            seq[e] = atomicAdd(&count[row_idx[e] * CPAD], 1);
    }
}

// Kernel 3a: per-block exclusive scan over PADDED counters, totals to bsums
__global__ void scan1_kernel(const int* __restrict__ in,
                             int* __restrict__ out,
                             int* __restrict__ bsums, int N) {
    __shared__ int tmp[SCAN_T];
    int tid = threadIdx.x, gid = blockIdx.x * SCAN_T + tid;
    int v = (gid < N) ? in[gid * CPAD] : 0;
    tmp[tid] = v;
    __syncthreads();
    for (int off = 1; off < SCAN_T; off <<= 1) {
        int t = (tid >= off) ? tmp[tid - off] : 0;
        __syncthreads();
        tmp[tid] += t;
        __syncthreads();
    }
    if (gid < N) out[gid] = tmp[tid] - v;          // exclusive
    if (tid == SCAN_T - 1) bsums[blockIdx.x] = tmp[tid];  // inclusive total
}

// Kernel 3b: single-block exclusive scan of block totals
__global__ void scan2_kernel(const int* __restrict__ bsums,
                             int* __restrict__ boffs, int B) {
    __shared__ int tmp[SCAN_T];
    int tid = threadIdx.x;
    int v = (tid < B) ? bsums[tid] : 0;
    tmp[tid] = v;
    __syncthreads();
    for (int off = 1; off < SCAN_T; off <<= 1) {
        int t = (tid >= off) ? tmp[tid - off] : 0;
        __syncthreads();
        tmp[tid] += t;
        __syncthreads();
    }
    if (tid < B) boffs[tid] = tmp[tid] - v;
}

// Kernel 3c: add block offsets -> row_start; row_start[N]=E
__global__ void scan3_kernel(int* __restrict__ row_start,
                             const int* __restrict__ boffs, int N, int E) {
    int gid = blockIdx.x * SCAN_T + threadIdx.x;
    if (gid < N) row_start[gid] += boffs[blockIdx.x];
    if (gid == 0) row_start[N] = E;
}

// Kernel 4: place col indices into CSR order — NO atomics. pos is a plain
// read-compute; scattered 4B store is fire-and-forget. 4 edges/thread.
__global__ void place_kernel(const int* __restrict__ row_idx,
                             const int* __restrict__ col_idx,
                             const int* __restrict__ seq,
                             const int* __restrict__ row_start,
                             int* __restrict__ col_sorted, int E) {
    int t = blockIdx.x * 256 + threadIdx.x;
    int e0 = t * 4;
    if (e0 + 3 < E) {
        int4 r = *(const int4*)(row_idx + e0);
        int4 c = *(const int4*)(col_idx + e0);
        int4 s = *(const int4*)(seq + e0);
        col_sorted[row_start[r.x] + s.x] = c.x;
        col_sorted[row_start[r.y] + s.y] = c.y;
        col_sorted[row_start[r.z] + s.z] = c.z;
        col_sorted[row_start[r.w] + s.w] = c.w;
    } else {
        for (int e = e0; e < E; e++)
            col_sorted[row_start[row_idx[e]] + seq[e]] = col_idx[e];
    }
}

// Kernel 5: fused per-row kernel. Wave per row, lane per feature.
// Per 16-edge chunk: 16 coalesced neighbor-row loads -> per-lane partials,
// butterfly multi-reduce -> 16 dots (dot j lands on lanes with lane&15==j),
// weight math once per wave for 16 edges, 16 shfl-broadcast FMAs aggregate.
__global__ void fused_kernel(const float* __restrict__ x,
                             const unsigned short* __restrict__ x_bf,
                             const float2* __restrict__ snf,
                             const int* __restrict__ col_sorted,
                             const int* __restrict__ row_start,
                             const float* __restrict__ beta,
                             const float* __restrict__ con,
                             float* __restrict__ out, int N) {
    int row = blockIdx.x * 4 + (threadIdx.x >> 6);
    int lane = threadIdx.x & 63;
    if (row >= N) return;
    int start = row_start[row];
    int end = row_start[row + 1];
    float xr = x[row * D + lane];       // this lane's feature of row r (fp32)
    float x2 = snf[row].x;
    float B = beta[0], C0 = con[0];
    int jj = lane & 15;                 // this lane's edge slot within a chunk
    float acc = 0.0f, wacc = 0.0f;

    for (int j0 = start; j0 < end; j0 += 16) {
        int c_own = (j0 + jj < end) ? col_sorted[j0 + jj] : 0;
        float xv[16];
        float v[16];
#pragma unroll
        for (int j = 0; j < 16; j++) {
            int cj = __shfl(c_own, j, 16);           // wave-uniform col j
            float xc = bf2f(x_bf[cj * D + lane]);    // coalesced 128B row
            xv[j] = xc;
            v[j] = xc * xr;                          // partial dot
        }
        // butterfly multi-reduce: 16 dots in 17 shfls.
#pragma unroll
        for (int k = 0; k < 4; k++) {
            bool hi = (lane >> k) & 1;
            int half = 8 >> k;
#pragma unroll
            for (int i = 0; i < half; i++) {
                float a = v[2 * i], b = v[2 * i + 1];
                float keep = hi ? b : a;
                float send = hi ? a : b;
                v[i] = keep + __shfl_xor(send, 1 << k, 64);
            }
        }
        float d = v[0];
        d += __shfl_xor(d, 16, 64);
        d += __shfl_xor(d, 32, 64);     // full 64-lane dot for edge jj

        // weight math: each lane handles its own edge jj (4 redundant copies)
        float2 sf = snf[c_own];         // (y2, f_col)
        float y2 = sf.x;
        float a_ = 1.0f - 2.0f * d + y2;
        float b_ = 1.0f - x2;
        float num2 = a_ * a_ * x2 - 2.0f * a_ * b_ * d + b_ * b_ * y2;
        float den = fmaxf(1.0f - 2.0f * d + x2 * y2, MIN_NORM);
        float man = sqrtf(fmaxf(num2, 0.0f)) * __builtin_amdgcn_rcpf(den);
        float at = fast_artanh(man);
        float w = __expf(-B * 4.0f * at * at + C0);  // dist^2 = 4*artanh^2
        if (j0 + jj >= end) w = 0.0f;                 // mask tail slots
        float wf = w * sf.y;
        wacc += w;
#pragma unroll
        for (int j = 0; j < 16; j++) {
            float wfj = __shfl(wf, j, 16);
            acc += wfj * xv[j];
        }
    }
    // wsum: reduce wacc within the 16-lane group (each group has all 16 edges)
#pragma unroll
    for (int m = 1; m < 16; m <<= 1)
        wacc += __shfl_xor(wacc, m, 64);

    float s = acc / (wacc + 1e-10f);
    float n2 = wave_reduce_sum(s * s);
    float un = fmaxf(sqrtf(n2), MIN_NORM);
    float tt = tanhf(un) / un;                     // expmap0 scale
    float o = tt * s;
    float on = tt * sqrtf(n2);                     // ||o||
    if (on > PROJ_MAXNORM)
        o = o / fmaxf(on, MIN_NORM) * PROJ_MAXNORM;
    out[row * D + lane] = o;
}

extern "C" void kernel_launch(void* const* d_in, const int* in_sizes, int n_in,
                              void* d_out, int out_size, void* d_ws, size_t ws_size,
                              hipStream_t stream) {
    const float* x    = (const float*)d_in[0];
    const float* beta = (const float*)d_in[1];
    const float* con  = (const float*)d_in[2];
    const int*   ei   = (const int*)d_in[3];

    int N = in_sizes[0] / D;
    int E = in_sizes[3] / 2;
    const int* row_idx = ei;
    const int* col_idx = ei + E;
    float* out = (float*)d_out;

    // workspace layout (8B-aligned first)
    float2*         snf   = (float2*)d_ws;                 // N float2 (800KB)
    unsigned short* x_bf  = (unsigned short*)(snf + N);    // N*D bf16 (12.8 MB)
    int*    col_sorted = (int*)(x_bf + (size_t)N * D);     // E ints (6.4 MB)
    int*    seq      = col_sorted + E;                     // E ints (6.4 MB)
    int*    count    = seq + E;                            // N*CPAD ints (6.4 MB)
    int*    row_start= count + (size_t)N * CPAD;           // N+1 ints
    int*    bsums    = row_start + N + 1;                  // SCAN_T ints
    int*    boffs    = bsums + SCAN_T;                     // SCAN_T ints

    hipMemsetAsync(count, 0, (size_t)N * CPAD * sizeof(int), stream);

    int nodeBlocks = (N + 3) / 4;
    prep_kernel<<<nodeBlocks, 256, 0, stream>>>(x, x_bf, snf, N);

    int edgeT = (E + 3) / 4;  // 4 edges per thread
    count_rank_kernel<<<(edgeT + 255) / 256, 256, 0, stream>>>(row_idx, count, seq, E);

    int SB = (N + SCAN_T - 1) / SCAN_T;   // 98 blocks for N=100K
    scan1_kernel<<<SB, SCAN_T, 0, stream>>>(count, row_start, bsums, N);
    scan2_kernel<<<1, SCAN_T, 0, stream>>>(bsums, boffs, SB);
    scan3_kernel<<<SB, SCAN_T, 0, stream>>>(row_start, boffs, N, E);

    place_kernel<<<(edgeT + 255) / 256, 256, 0, stream>>>(row_idx, col_idx, seq,
                                                          row_start, col_sorted, E);

    fused_kernel<<<nodeBlocks, 256, 0, stream>>>(x, x_bf, snf, col_sorted,
                                                 row_start, beta, con, out, N);
}

// Round 8
// 257.228 us; speedup vs baseline: 1.4790x; 1.1244x over previous
//
#include <hip/hip_runtime.h>
#include <math.h>

#define D 64
#define MIN_NORM 1e-15f
#define PROJ_MAXNORM 0.996f   // (1 - 4e-3) / sqrt(c), c=1
#define SCAN_T 1024
#define CPAD 16               // one counter per 64B cache line

typedef __attribute__((ext_vector_type(8))) short short8;   // 8 bf16 (4 VGPR)
typedef __attribute__((ext_vector_type(4))) float float4_;  // MFMA C/D

__device__ __forceinline__ float wave_reduce_sum(float v) {
#pragma unroll
    for (int m = 1; m < 64; m <<= 1)
        v += __shfl_xor(v, m, 64);
    return v;
}

// artanh for z >= 0 (input is a norm), fast log + rcp
__device__ __forceinline__ float fast_artanh(float z) {
    z = fminf(z, 1.0f - 1e-7f);
    return 0.5f * __logf((1.0f + z) * __builtin_amdgcn_rcpf(1.0f - z));
}

__device__ __forceinline__ unsigned short f2bf(float x) {  // RNE
    unsigned int b = __float_as_uint(x);
    return (unsigned short)((b + 0x7fffu + ((b >> 16) & 1u)) >> 16);
}

__device__ __forceinline__ float bf2f(unsigned short u) {
    return __uint_as_float(((unsigned int)u) << 16);
}

// Kernel 1: bf16 copy of x + packed (sqnorm, logmap0-scale); also zeroes the
// padded count array (fuses the old memset launch).
__global__ void prep_kernel(const float* __restrict__ x,
                            unsigned short* __restrict__ x_bf,
                            float2* __restrict__ snf,
                            int* __restrict__ count,
                            int N, int CN) {
    int gid = blockIdx.x * 256 + threadIdx.x;
    if (gid < CN) count[gid] = 0;
    int node = blockIdx.x * 4 + (threadIdx.x >> 6);
    int lane = threadIdx.x & 63;
    if (node >= N) return;
    float v = x[node * D + lane];
    float s = wave_reduce_sum(v * v);
    float pn = fmaxf(sqrtf(s), MIN_NORM);
    float f = fast_artanh(pn) / pn;
    x_bf[node * D + lane] = f2bf(v);
    if (lane == 0) snf[node] = make_float2(s, f);
}

// Kernel 2: count + rank in one pass (padded counters, 4 edges/thread,
// coalesced seq store).
__global__ void count_rank_kernel(const int* __restrict__ row_idx,
                                  int* __restrict__ count,
                                  int* __restrict__ seq, int E) {
    int t = blockIdx.x * 256 + threadIdx.x;
    int e0 = t * 4;
    if (e0 + 3 < E) {
        int4 r = *(const int4*)(row_idx + e0);
        int4 s;
        s.x = atomicAdd(&count[r.x * CPAD], 1);
        s.y = atomicAdd(&count[r.y * CPAD], 1);
        s.z = atomicAdd(&count[r.z * CPAD], 1);
        s.w = atomicAdd(&count[r.w * CPAD], 1);
        *(int4*)(seq + e0) = s;
    } else {
        for (int e = e0; e < E; e++)
            seq[e] = atomicAdd(&count[row_idx[e] * CPAD], 1);
    }
}

// Kernel 3a: per-block exclusive scan over PADDED counters, totals to bsums
__global__ void scan1_kernel(const int* __restrict__ in,
                             int* __restrict__ out,
                             int* __restrict__ bsums, int N) {
    __shared__ int tmp[SCAN_T];
    int tid = threadIdx.x, gid = blockIdx.x * SCAN_T + tid;
    int v = (gid < N) ? in[gid * CPAD] : 0;
    tmp[tid] = v;
    __syncthreads();
    for (int off = 1; off < SCAN_T; off <<= 1) {
        int t = (tid >= off) ? tmp[tid - off] : 0;
        __syncthreads();
        tmp[tid] += t;
        __syncthreads();
    }
    if (gid < N) out[gid] = tmp[tid] - v;          // exclusive
    if (tid == SCAN_T - 1) bsums[blockIdx.x] = tmp[tid];  // inclusive total
}

// Kernel 3b: single-block exclusive scan of block totals
__global__ void scan2_kernel(const int* __restrict__ bsums,
                             int* __restrict__ boffs, int B) {
    __shared__ int tmp[SCAN_T];
    int tid = threadIdx.x;
    int v = (tid < B) ? bsums[tid] : 0;
    tmp[tid] = v;
    __syncthreads();
    for (int off = 1; off < SCAN_T; off <<= 1) {
        int t = (tid >= off) ? tmp[tid - off] : 0;
        __syncthreads();
        tmp[tid] += t;
        __syncthreads();
    }
    if (tid < B) boffs[tid] = tmp[tid] - v;
}

// Kernel 3c: add block offsets -> row_start; row_start[N]=E
__global__ void scan3_kernel(int* __restrict__ row_start,
                             const int* __restrict__ boffs, int N, int E) {
    int gid = blockIdx.x * SCAN_T + threadIdx.x;
    if (gid < N) row_start[gid] += boffs[blockIdx.x];
    if (gid == 0) row_start[N] = E;
}

// Kernel 4: place col indices into CSR order — no atomics, 4 edges/thread.
__global__ void place_kernel(const int* __restrict__ row_idx,
                             const int* __restrict__ col_idx,
                             const int* __restrict__ seq,
                             const int* __restrict__ row_start,
                             int* __restrict__ col_sorted, int E) {
    int t = blockIdx.x * 256 + threadIdx.x;
    int e0 = t * 4;
    if (e0 + 3 < E) {
        int4 r = *(const int4*)(row_idx + e0);
        int4 c = *(const int4*)(col_idx + e0);
        int4 s = *(const int4*)(seq + e0);
        col_sorted[row_start[r.x] + s.x] = c.x;
        col_sorted[row_start[r.y] + s.y] = c.y;
        col_sorted[row_start[r.z] + s.z] = c.z;
        col_sorted[row_start[r.w] + s.w] = c.w;
    } else {
        for (int e = e0; e < E; e++)
            col_sorted[row_start[row_idx[e]] + seq[e]] = col_idx[e];
    }
}

// Kernel 5: fused per-row kernel, MFMA dots + per-lane aggregation.
// Wave per row. Per 16-edge chunk:
//  - lane l loads neighbor (l&15)'s features [(l>>4)*8,+8) and [32+(l>>4)*8,+8)
//    as two short8 (A operand, m=neighbor, k=feature)
//  - B operand = row-r features broadcast over N (loaded once per row)
//  - 2x mfma_f32_16x16x32_bf16 -> all 16 dots; 16B LDS round-trip lands
//    dot j on lanes with lane&15==j
//  - weight math per lane (its own edge), then 16 per-lane FMAs accumulate
//    wf * neighbor-features (no shfl at all in the loop)
// Epilogue: LDS transpose back to lane-per-feature, expmap0+proj, coalesced store.
__global__ void fused_kernel(const unsigned short* __restrict__ x_bf,
                             const float2* __restrict__ snf,
                             const int* __restrict__ col_sorted,
                             const int* __restrict__ row_start,
                             const float* __restrict__ beta,
                             const float* __restrict__ con,
                             float* __restrict__ out, int N) {
    __shared__ float lds[4][1024];     // 4 KB per wave
    int wid = threadIdx.x >> 6;
    int lane = threadIdx.x & 63;
    int row = blockIdx.x * 4 + wid;
    if (row >= N) return;
    float* myLds = lds[wid];
    int start = row_start[row];
    int end = row_start[row + 1];
    int jj = lane & 15;
    int qd = lane >> 4;

    // B operand: every lane in quad q holds xr[q*8 + j] (and +32 for mfma2)
    const unsigned short* xr = x_bf + (size_t)row * D + qd * 8;
    short8 bfr0 = *(const short8*)xr;
    short8 bfr1 = *(const short8*)(xr + 32);
    float x2 = snf[row].x;
    float B = beta[0], C0 = con[0];

    float acc[16];
#pragma unroll
    for (int i = 0; i < 16; i++) acc[i] = 0.0f;
    float wacc = 0.0f;
    float4_ zero4 = {0.0f, 0.0f, 0.0f, 0.0f};

    for (int j0 = start; j0 < end; j0 += 16) {
        int idx = j0 + jj;
        bool valid = idx < end;
        int cw = col_sorted[valid ? idx : end - 1];
        const unsigned short* rp = x_bf + (size_t)cw * D + qd * 8;
        short8 af0 = *(const short8*)rp;          // features [qd*8, +8)
        short8 af1 = *(const short8*)(rp + 32);   // features [32+qd*8, +8)
        float2 sf = snf[cw];                      // (y2, f_col)

        float4_ d4 = __builtin_amdgcn_mfma_f32_16x16x32_bf16(af0, bfr0, zero4, 0, 0, 0);
        d4 = __builtin_amdgcn_mfma_f32_16x16x32_bf16(af1, bfr1, d4, 0, 0, 0);
        // d4 reg r = dot for edge m = qd*4 + r (all 16 cols identical)

        __builtin_amdgcn_wave_barrier();
        if (jj == 0)
            *(float4_*)&myLds[qd * 4] = *(float4_*)&d4;   // dots 0..15
        __builtin_amdgcn_wave_barrier();
        float d = myLds[jj];                               // dot for my edge
        __builtin_amdgcn_wave_barrier();

        // weight math: each lane handles edge jj (4 redundant copies)
        float y2 = sf.x;
        float a_ = 1.0f - 2.0f * d + y2;
        float b_ = 1.0f - x2;
        float num2 = a_ * a_ * x2 - 2.0f * a_ * b_ * d + b_ * b_ * y2;
        float den = fmaxf(1.0f - 2.0f * d + x2 * y2, MIN_NORM);
        float man = sqrtf(fmaxf(num2, 0.0f)) * __builtin_amdgcn_rcpf(den);
        float at = fast_artanh(man);
        float w = __expf(-B * 4.0f * at * at + C0);  // dist^2 = 4*artanh^2
        w = valid ? w : 0.0f;
        float wf = w * sf.y;
        wacc += w;
#pragma unroll
        for (int j = 0; j < 8; j++) {
            acc[j]     += wf * bf2f((unsigned short)af0[j]);
            acc[8 + j] += wf * bf2f((unsigned short)af1[j]);
        }
    }

    // wsum: sum w over the 16-lane group (each group holds all 16 edges once)
#pragma unroll
    for (int m = 1; m < 16; m <<= 1)
        wacc += __shfl_xor(wacc, m, 64);

    // transpose acc back to lane-per-feature via LDS
    __builtin_amdgcn_wave_barrier();
#pragma unroll
    for (int k = 0; k < 4; k++)
        *(float4_*)&myLds[lane * 16 + k * 4] = *(float4_*)&acc[k * 4];
    __builtin_amdgcn_wave_barrier();
    // feature f=lane is held by lanes l with l>>4 == (f&31)>>3, at partial
    // index (f&7) + 8*(f>>5); sum their 16 contributions.
    int q = (lane & 31) >> 3;
    int pidx = (lane & 7) + 8 * (lane >> 5);
    float s = 0.0f;
#pragma unroll
    for (int i = 0; i < 16; i++)
        s += myLds[(q * 16 + i) * 16 + pidx];
    __builtin_amdgcn_wave_barrier();

    s = s * __builtin_amdgcn_rcpf(wacc + 1e-10f);
    float n2 = wave_reduce_sum(s * s);
    float un = fmaxf(sqrtf(n2), MIN_NORM);
    float tt = tanhf(un) / un;                     // expmap0 scale
    float o = tt * s;
    float on = tt * sqrtf(n2);                     // ||o||
    if (on > PROJ_MAXNORM)
        o = o / fmaxf(on, MIN_NORM) * PROJ_MAXNORM;
    out[row * D + lane] = o;
}

extern "C" void kernel_launch(void* const* d_in, const int* in_sizes, int n_in,
                              void* d_out, int out_size, void* d_ws, size_t ws_size,
                              hipStream_t stream) {
    const float* x    = (const float*)d_in[0];
    const float* beta = (const float*)d_in[1];
    const float* con  = (const float*)d_in[2];
    const int*   ei   = (const int*)d_in[3];

    int N = in_sizes[0] / D;
    int E = in_sizes[3] / 2;
    const int* row_idx = ei;
    const int* col_idx = ei + E;
    float* out = (float*)d_out;

    // workspace layout (8B-aligned first)
    float2*         snf   = (float2*)d_ws;                 // N float2 (800KB)
    unsigned short* x_bf  = (unsigned short*)(snf + N);    // N*D bf16 (12.8 MB)
    int*    col_sorted = (int*)(x_bf + (size_t)N * D);     // E ints (6.4 MB)
    int*    seq      = col_sorted + E;                     // E ints (6.4 MB)
    int*    count    = seq + E;                            // N*CPAD ints (6.4 MB)
    int*    row_start= count + (size_t)N * CPAD;           // N+1 ints
    int*    bsums    = row_start + N + 1;                  // SCAN_T ints
    int*    boffs    = bsums + SCAN_T;                     // SCAN_T ints

    int nodeBlocks = (N + 3) / 4;
    prep_kernel<<<nodeBlocks, 256, 0, stream>>>(x, x_bf, snf, count, N, N * CPAD);

    int edgeT = (E + 3) / 4;  // 4 edges per thread
    count_rank_kernel<<<(edgeT + 255) / 256, 256, 0, stream>>>(row_idx, count, seq, E);

    int SB = (N + SCAN_T - 1) / SCAN_T;   // 98 blocks for N=100K
    scan1_kernel<<<SB, SCAN_T, 0, stream>>>(count, row_start, bsums, N);
    scan2_kernel<<<1, SCAN_T, 0, stream>>>(bsums, boffs, SB);
    scan3_kernel<<<SB, SCAN_T, 0, stream>>>(row_start, boffs, N, E);

    place_kernel<<<(edgeT + 255) / 256, 256, 0, stream>>>(row_idx, col_idx, seq,
                                                          row_start, col_sorted, E);

    fused_kernel<<<nodeBlocks, 256, 0, stream>>>(x_bf, snf, col_sorted,
                                                 row_start, beta, con, out, N);
}